// Round 4
// baseline (360.808 us; speedup 1.0000x reference)
//
#include <hip/hip_runtime.h>

#define BB   128
#define JJ   17
#define YY   96
#define XX   72
#define YX   (YY * XX)        // 6912 floats per (b,j) per channel
#define N4   (YX / 4)         // 1728 float4s
#define NQ   (BB * JJ)        // 2176 blocks / partials
#define NTOT (NQ * YX)        // 15040512 elements per channel
#define UNI  6                // uniform float4 iters/thread (6*256 = 1536)
#define TAIL (N4 - UNI * 256) // 192 remaining float4s (threads 0..191)

// Sum of squared diffs for one float4 pair at float4-index i within a q-tile.
// yy = (4i)/72 = i/18 ; xx = (i%18)*4. gt uses trunc-toward-zero (np int32 cast).
__device__ __forceinline__ float tile_term(float4 lx, float4 ly, int i,
                                           float cx, float cy) {
    const int yy = i / 18;                // magic-mul constant divide
    const int xx = (i - yy * 18) * 4;
    const float gy = (float)(int)((float)yy - cy);
    float s = 0.0f;
    #pragma unroll
    for (int k = 0; k < 4; ++k) {
        const float gx = (float)(int)((float)(xx + k) - cx);
        const float dx = (&lx.x)[k] - gx;
        s = fmaf(dx, dx, s);
        const float dy = (&ly.x)[k] - gy;
        s = fmaf(dy, dy, s);
    }
    return s;
}

// Fused: per-q partial sums + last-block final reduction (threadfence-reduction
// pattern, expressed with agent-scope atomics for cross-XCD correctness).
__global__ __launch_bounds__(256) void regloss_fused_kernel(
    const float* __restrict__ loc,     // (2, B, J, Y, X)
    const float* __restrict__ cord,    // (2, J, B)
    const float* __restrict__ tw,      // (B, J, 1)
    float* __restrict__ partial,       // (NQ,) in d_ws
    unsigned int* __restrict__ counter,// 1 uint in d_ws, memset to 0 pre-launch
    float* __restrict__ out)
{
    const int tid = threadIdx.x;
    const int q  = blockIdx.x;
    const int jj = q >> 7;            // q / 128
    const int bb = q & 127;           // q % 128

    const float cx = cord[jj * BB + bb];
    const float cy = cord[JJ * BB + jj * BB + bb];
    const float w  = tw[q];

    const float4* loc0 = (const float4*)(loc + (size_t)q * YX);
    const float4* loc1 = (const float4*)(loc + (size_t)NTOT + (size_t)q * YX);

    // Batch all loads up-front for max memory-level parallelism.
    float4 lx[UNI + 1], ly[UNI + 1];
    #pragma unroll
    for (int k = 0; k < UNI; ++k) lx[k] = loc0[tid + 256 * k];
    #pragma unroll
    for (int k = 0; k < UNI; ++k) ly[k] = loc1[tid + 256 * k];
    const bool has_tail = tid < TAIL;
    if (has_tail) {
        lx[UNI] = loc0[UNI * 256 + tid];
        ly[UNI] = loc1[UNI * 256 + tid];
    }

    float acc = 0.0f;
    #pragma unroll
    for (int k = 0; k < UNI; ++k)
        acc += tile_term(lx[k], ly[k], tid + 256 * k, cx, cy);
    if (has_tail)
        acc += tile_term(lx[UNI], ly[UNI], UNI * 256 + tid, cx, cy);

    // wave64 shuffle reduction
    #pragma unroll
    for (int off = 32; off > 0; off >>= 1)
        acc += __shfl_down(acc, off, 64);

    __shared__ float wsum[4];
    __shared__ bool  is_last;
    const int lane = tid & 63;
    const int wave = tid >> 6;
    if (lane == 0) wsum[wave] = acc;
    __syncthreads();

    if (tid == 0) {
        const float p = (w * w) * (wsum[0] + wsum[1] + wsum[2] + wsum[3]);
        __hip_atomic_store(&partial[q], p, __ATOMIC_RELEASE,
                           __HIP_MEMORY_SCOPE_AGENT);
        const unsigned old = __hip_atomic_fetch_add(counter, 1u,
                           __ATOMIC_ACQ_REL, __HIP_MEMORY_SCOPE_AGENT);
        is_last = (old == NQ - 1);
    }
    __syncthreads();

    if (is_last) {
        // Last block folds all partials; agent-scope loads bypass stale L1/L2.
        float a2 = 0.0f;
        for (int i = tid; i < NQ; i += 256)
            a2 += __hip_atomic_load(&partial[i], __ATOMIC_RELAXED,
                                    __HIP_MEMORY_SCOPE_AGENT);
        #pragma unroll
        for (int off = 32; off > 0; off >>= 1)
            a2 += __shfl_down(a2, off, 64);
        if (lane == 0) wsum[wave] = a2;
        __syncthreads();
        if (tid == 0) {
            const float s = wsum[0] + wsum[1] + wsum[2] + wsum[3];
            out[0] = s * (0.5f / (float)NTOT);   // 0.5 / (J * B * YX)
        }
    }
}

extern "C" void kernel_launch(void* const* d_in, const int* in_sizes, int n_in,
                              void* d_out, int out_size, void* d_ws, size_t ws_size,
                              hipStream_t stream) {
    const float* loc  = (const float*)d_in[0];   // (2,128,17,96,72) fp32
    const float* cord = (const float*)d_in[1];   // (2,17,128) fp32
    const float* tw   = (const float*)d_in[2];   // (128,17,1) fp32
    float* partial = (float*)d_ws;               // NQ floats
    unsigned int* counter = (unsigned int*)((float*)d_ws + NQ);
    float* out = (float*)d_out;

    hipMemsetAsync(counter, 0, sizeof(unsigned int), stream);  // capture-safe
    regloss_fused_kernel<<<NQ, 256, 0, stream>>>(loc, cord, tw, partial,
                                                 counter, out);
}

// Round 5
// 177.197 us; speedup vs baseline: 2.0362x; 2.0362x over previous
//
#include <hip/hip_runtime.h>

#define BB   128
#define JJ   17
#define YY   96
#define XX   72
#define YX   (YY * XX)        // 6912 floats per (b,j) per channel
#define N4   (YX / 4)         // 1728 float4s
#define NQ   (BB * JJ)        // 2176 blocks / partials
#define NTOT (NQ * YX)        // 15040512 elements per channel
#define UNI  6                // uniform float4 iters/thread (6*256 = 1536)
#define TAIL (N4 - UNI * 256) // 192 remaining float4s (threads 0..191)

// Sum of squared diffs for one float4 pair at float4-index i within a q-tile.
// yy = (4i)/72 = i/18 ; xx = (i%18)*4. gt uses trunc-toward-zero (np int32 cast).
__device__ __forceinline__ float tile_term(float4 lx, float4 ly, int i,
                                           float cx, float cy) {
    const int yy = i / 18;                // magic-mul constant divide
    const int xx = (i - yy * 18) * 4;
    const float gy = (float)(int)((float)yy - cy);
    float s = 0.0f;
    #pragma unroll
    for (int k = 0; k < 4; ++k) {
        const float gx = (float)(int)((float)(xx + k) - cx);
        const float dx = (&lx.x)[k] - gx;
        s = fmaf(dx, dx, s);
        const float dy = (&ly.x)[k] - gy;
        s = fmaf(dy, dy, s);
    }
    return s;
}

// Stage 1: one block per q = b*J + j. Plain stores of per-block partials;
// the kernel boundary provides the (cheap) device-wide ordering. NOTE (R4
// post-mortem): do NOT fuse with agent-scope release/acquire atomics — each
// block's fence emits buffer_wbl2/buffer_inv, 2176 L2 flushes, +186 us.
__global__ __launch_bounds__(256) void regloss_partial_kernel(
    const float* __restrict__ loc,    // (2, B, J, Y, X)
    const float* __restrict__ cord,   // (2, J, B)
    const float* __restrict__ tw,     // (B, J, 1)
    float* __restrict__ partial)      // (NQ,) in d_ws
{
    const int tid = threadIdx.x;
    const int q  = blockIdx.x;
    const int jj = q >> 7;            // q / 128
    const int bb = q & 127;           // q % 128

    const float cx = cord[jj * BB + bb];
    const float cy = cord[JJ * BB + jj * BB + bb];
    const float w  = tw[q];

    const float4* loc0 = (const float4*)(loc + (size_t)q * YX);
    const float4* loc1 = (const float4*)(loc + (size_t)NTOT + (size_t)q * YX);

    // Batch loads up-front for memory-level parallelism.
    float4 lx[UNI + 1], ly[UNI + 1];
    #pragma unroll
    for (int k = 0; k < UNI; ++k) lx[k] = loc0[tid + 256 * k];
    #pragma unroll
    for (int k = 0; k < UNI; ++k) ly[k] = loc1[tid + 256 * k];
    const bool has_tail = tid < TAIL;
    if (has_tail) {
        lx[UNI] = loc0[UNI * 256 + tid];
        ly[UNI] = loc1[UNI * 256 + tid];
    }

    float acc = 0.0f;
    #pragma unroll
    for (int k = 0; k < UNI; ++k)
        acc += tile_term(lx[k], ly[k], tid + 256 * k, cx, cy);
    if (has_tail)
        acc += tile_term(lx[UNI], ly[UNI], UNI * 256 + tid, cx, cy);

    // wave64 shuffle reduction
    #pragma unroll
    for (int off = 32; off > 0; off >>= 1)
        acc += __shfl_down(acc, off, 64);

    __shared__ float wsum[4];
    const int lane = tid & 63;
    const int wave = tid >> 6;
    if (lane == 0) wsum[wave] = acc;
    __syncthreads();

    if (tid == 0)   // w is uniform per block: apply w^2 once here
        partial[q] = (w * w) * (wsum[0] + wsum[1] + wsum[2] + wsum[3]);
}

// Stage 2: single block folds the 2176 partials, scales, stores the scalar.
__global__ __launch_bounds__(256) void regloss_final_kernel(
    const float* __restrict__ partial, float* __restrict__ out)
{
    float acc = 0.0f;
    for (int i = threadIdx.x; i < NQ; i += 256)
        acc += partial[i];

    #pragma unroll
    for (int off = 32; off > 0; off >>= 1)
        acc += __shfl_down(acc, off, 64);

    __shared__ float wsum[4];
    const int lane = threadIdx.x & 63;
    const int wave = threadIdx.x >> 6;
    if (lane == 0) wsum[wave] = acc;
    __syncthreads();

    if (threadIdx.x == 0) {
        const float s = wsum[0] + wsum[1] + wsum[2] + wsum[3];
        out[0] = s * (0.5f / (float)NTOT);   // 0.5 / (J * B * YX)
    }
}

extern "C" void kernel_launch(void* const* d_in, const int* in_sizes, int n_in,
                              void* d_out, int out_size, void* d_ws, size_t ws_size,
                              hipStream_t stream) {
    const float* loc  = (const float*)d_in[0];   // (2,128,17,96,72) fp32
    const float* cord = (const float*)d_in[1];   // (2,17,128) fp32
    const float* tw   = (const float*)d_in[2];   // (128,17,1) fp32
    float* partial = (float*)d_ws;               // NQ floats, overwritten each call
    float* out = (float*)d_out;

    regloss_partial_kernel<<<NQ, 256, 0, stream>>>(loc, cord, tw, partial);
    regloss_final_kernel<<<1, 256, 0, stream>>>(partial, out);
}

// Round 6
// 175.830 us; speedup vs baseline: 2.0520x; 1.0078x over previous
//
#include <hip/hip_runtime.h>

#define BB   128
#define JJ   17
#define YY   96
#define XX   72
#define YX   (YY * XX)        // 6912 floats per (b,j) per channel
#define N4   (YX / 4)         // 1728 float4s per tile
#define NQ   (BB * JJ)        // 2176 q-tiles
#define NB   (NQ / 2)         // 1088 blocks, two q-tiles each
#define NTOT (NQ * YX)        // 15040512 elements per channel
#define UNI  6                // uniform float4 iters/thread (6*256 = 1536)
#define TAIL (N4 - UNI * 256) // 192 remaining float4s (threads 0..191)

// Sum of squared diffs for one float4 pair at float4-index i within a q-tile.
// yy = (4i)/72 = i/18 ; xx = (i%18)*4. gt uses trunc-toward-zero (np int32 cast).
__device__ __forceinline__ float tile_term(float4 lx, float4 ly, int i,
                                           float cx, float cy) {
    const int yy = i / 18;                // magic-mul constant divide
    const int xx = (i - yy * 18) * 4;
    const float gy = (float)(int)((float)yy - cy);
    float s = 0.0f;
    #pragma unroll
    for (int k = 0; k < 4; ++k) {
        const float gx = (float)(int)((float)(xx + k) - cx);
        const float dx = (&lx.x)[k] - gx;
        s = fmaf(dx, dx, s);
        const float dy = (&ly.x)[k] - gy;
        s = fmaf(dy, dy, s);
    }
    return s;
}

// Per-thread sum over one q-tile (both channels), loads batched up-front.
__device__ __forceinline__ float tile_sum(const float* __restrict__ loc,
                                          int q, int tid,
                                          float cx, float cy) {
    const float4* loc0 = (const float4*)(loc + (size_t)q * YX);
    const float4* loc1 = (const float4*)(loc + (size_t)NTOT + (size_t)q * YX);

    float4 lx[UNI + 1], ly[UNI + 1];
    #pragma unroll
    for (int k = 0; k < UNI; ++k) lx[k] = loc0[tid + 256 * k];
    #pragma unroll
    for (int k = 0; k < UNI; ++k) ly[k] = loc1[tid + 256 * k];
    const bool has_tail = tid < TAIL;
    if (has_tail) {
        lx[UNI] = loc0[UNI * 256 + tid];
        ly[UNI] = loc1[UNI * 256 + tid];
    }

    float s = 0.0f;
    #pragma unroll
    for (int k = 0; k < UNI; ++k)
        s += tile_term(lx[k], ly[k], tid + 256 * k, cx, cy);
    if (has_tail)
        s += tile_term(lx[UNI], ly[UNI], UNI * 256 + tid, cx, cy);
    return s;
}

// Stage 1: one block per PAIR of q-tiles -> 1088 blocks x 4 waves = 4352
// waves = 17/CU: a single resident generation (R5 theory: 2176 blocks =
// 34 waves/CU forced a second, latency-limited straggler generation).
// NOTE (R4 post-mortem): do NOT fuse stage 2 in via agent-scope
// release/acquire atomics — per-block buffer_wbl2/buffer_inv cost +186 us.
__global__ __launch_bounds__(256) void regloss_partial_kernel(
    const float* __restrict__ loc,    // (2, B, J, Y, X)
    const float* __restrict__ cord,   // (2, J, B)
    const float* __restrict__ tw,     // (B, J, 1)
    float* __restrict__ partial)      // (NB,) in d_ws
{
    const int tid = threadIdx.x;
    const int q0  = blockIdx.x * 2;
    const int q1  = q0 + 1;
    const int jj0 = q0 >> 7, bb0 = q0 & 127;
    const int jj1 = q1 >> 7, bb1 = q1 & 127;

    const float cx0 = cord[jj0 * BB + bb0];
    const float cy0 = cord[JJ * BB + jj0 * BB + bb0];
    const float w0  = tw[q0];
    const float cx1 = cord[jj1 * BB + bb1];
    const float cy1 = cord[JJ * BB + jj1 * BB + bb1];
    const float w1  = tw[q1];

    const float s0 = tile_sum(loc, q0, tid, cx0, cy0);
    const float s1 = tile_sum(loc, q1, tid, cx1, cy1);
    float acc = fmaf(w0 * w0, s0, (w1 * w1) * s1);

    // wave64 shuffle reduction
    #pragma unroll
    for (int off = 32; off > 0; off >>= 1)
        acc += __shfl_down(acc, off, 64);

    __shared__ float wsum[4];
    const int lane = tid & 63;
    const int wave = tid >> 6;
    if (lane == 0) wsum[wave] = acc;
    __syncthreads();

    if (tid == 0)
        partial[blockIdx.x] = wsum[0] + wsum[1] + wsum[2] + wsum[3];
}

// Stage 2: single block folds the 1088 partials, scales, stores the scalar.
__global__ __launch_bounds__(256) void regloss_final_kernel(
    const float* __restrict__ partial, float* __restrict__ out)
{
    float acc = 0.0f;
    for (int i = threadIdx.x; i < NB; i += 256)
        acc += partial[i];

    #pragma unroll
    for (int off = 32; off > 0; off >>= 1)
        acc += __shfl_down(acc, off, 64);

    __shared__ float wsum[4];
    const int lane = threadIdx.x & 63;
    const int wave = threadIdx.x >> 6;
    if (lane == 0) wsum[wave] = acc;
    __syncthreads();

    if (threadIdx.x == 0) {
        const float s = wsum[0] + wsum[1] + wsum[2] + wsum[3];
        out[0] = s * (0.5f / (float)NTOT);   // 0.5 / (J * B * YX)
    }
}

extern "C" void kernel_launch(void* const* d_in, const int* in_sizes, int n_in,
                              void* d_out, int out_size, void* d_ws, size_t ws_size,
                              hipStream_t stream) {
    const float* loc  = (const float*)d_in[0];   // (2,128,17,96,72) fp32
    const float* cord = (const float*)d_in[1];   // (2,17,128) fp32
    const float* tw   = (const float*)d_in[2];   // (128,17,1) fp32
    float* partial = (float*)d_ws;               // NB floats, overwritten each call
    float* out = (float*)d_out;

    regloss_partial_kernel<<<NB, 256, 0, stream>>>(loc, cord, tw, partial);
    regloss_final_kernel<<<1, 256, 0, stream>>>(partial, out);
}